// Round 16
// baseline (323.143 us; speedup 1.0000x reference)
//
#include <hip/hip_runtime.h>

#define NN 20000
#define NP 20096   // padded rows (multiple of 128)
#define NE 320000
#define DD 512

typedef __bf16 bf16x8 __attribute__((ext_vector_type(8)));
typedef float f32x4 __attribute__((ext_vector_type(4)));
typedef float f32x2 __attribute__((ext_vector_type(2)));
typedef unsigned short u16;

// fast transcendentals: v_exp_f32 + v_rcp_f32, branchless
__device__ __forceinline__ float sigmoidf_(float x) {
  return __builtin_amdgcn_rcpf(1.f + __expf(-x));
}
__device__ __forceinline__ float tanhf_(float x) {
  float xc = fminf(fmaxf(x, -15.f), 15.f);
  float u = __expf(2.f * xc);
  return (u - 1.f) * __builtin_amdgcn_rcpf(u + 1.f);
}

__device__ __forceinline__ unsigned bf16pair(float a, float b) {
  unsigned ua = __builtin_bit_cast(unsigned, a);
  unsigned ub = __builtin_bit_cast(unsigned, b);
  ua = (ua + 0x7FFFu + ((ua >> 16) & 1u)) >> 16;
  ub = (ub + 0x7FFFu + ((ub >> 16) & 1u)) >> 16;
  return ua | (ub << 16);
}
__device__ __forceinline__ u16 bf16one(float a) {
  unsigned ua = __builtin_bit_cast(unsigned, a);
  return (u16)((ua + 0x7FFFu + ((ua >> 16) & 1u)) >> 16);
}
__device__ __forceinline__ float bflo(unsigned w) { return __builtin_bit_cast(float, w << 16); }
__device__ __forceinline__ float bfhi(unsigned w) { return __builtin_bit_cast(float, w & 0xFFFF0000u); }
__device__ __forceinline__ float bf2f(u16 v) { return __builtin_bit_cast(float, (unsigned)v << 16); }

__device__ __forceinline__ void gload16(const void* g, void* l) {
  __builtin_amdgcn_global_load_lds(
      (const __attribute__((address_space(1))) unsigned int*)g,
      (__attribute__((address_space(3))) unsigned int*)l, 16, 0, 0);
}

// WtAll layout (bf16 elements):
//   Wcat_z [512][1024] at 0        (cols 0-511 = Wxz^T, 512-1023 = Whz^T)
//   Wcat_r [512][1024] at 524288
//   Wxh_t  [512][512]  at 1048576
//   Whh_t  [512][512]  at 1310720
#define OFF_WZ 0
#define OFF_WR 524288
#define OFF_WXH 1048576
#define OFF_WHH 1310720

// ---------------- fused setup: cvt(X,H)->bf16 | init deg/cnt | 6 weight transposes ----
#define CVT_B 10000   // 2*NN*DD/8/256
#define INIT_B 79     // ceil(NN/256)
#define WT_B 1536     // 6 * 16 * 16
__global__ __launch_bounds__(256) void k_setup(
    const float* __restrict__ X, const float* __restrict__ H,
    u16* __restrict__ Xb, u16* __restrict__ Hb,
    const float* __restrict__ W0, const float* __restrict__ W1,
    const float* __restrict__ W2, const float* __restrict__ W3,
    const float* __restrict__ W4, const float* __restrict__ W5,
    u16* __restrict__ T, float* __restrict__ deg, int* __restrict__ cnt) {
  __shared__ float t[32][33];
  int b = blockIdx.x;
  if (b < CVT_B) {
    const int n8 = NN * DD / 8;
    int i = b * 256 + threadIdx.x;
    const float* src = (i < n8) ? X : H;
    u16* dst = (i < n8) ? Xb : Hb;
    int k = (i < n8) ? i : i - n8;
    const float4* s = (const float4*)src;
    float4 v0 = s[k * 2], v1 = s[k * 2 + 1];
    uint4 o = {bf16pair(v0.x, v0.y), bf16pair(v0.z, v0.w),
               bf16pair(v1.x, v1.y), bf16pair(v1.z, v1.w)};
    ((uint4*)dst)[k] = o;
  } else if (b < CVT_B + INIT_B) {
    int i = (b - CVT_B) * 256 + threadIdx.x;
    if (i < NN) { deg[i] = 1.0f; cnt[i] = 0; }
  } else {
    int wb = b - CVT_B - INIT_B;          // [0, 1536)
    int mat = wb >> 8;
    const float* Wsrc;
    switch (mat) {
      case 0: Wsrc = W0; break; case 1: Wsrc = W1; break; case 2: Wsrc = W2; break;
      case 3: Wsrc = W3; break; case 4: Wsrc = W4; break; default: Wsrc = W5; break;
    }
    u16* dst;
    int stride, colOff;
    switch (mat) {
      case 0: dst = T + OFF_WZ;  stride = 1024; colOff = 0;   break;
      case 1: dst = T + OFF_WZ;  stride = 1024; colOff = 512; break;
      case 2: dst = T + OFF_WR;  stride = 1024; colOff = 0;   break;
      case 3: dst = T + OFF_WR;  stride = 1024; colOff = 512; break;
      case 4: dst = T + OFF_WXH; stride = 512;  colOff = 0;   break;
      default: dst = T + OFF_WHH; stride = 512; colOff = 0;   break;
    }
    int rb = wb & 255;
    int kb = (rb & 15) * 32, nb = (rb >> 4) * 32;
    int tx = threadIdx.x & 31, ty = threadIdx.x >> 5;
#pragma unroll
    for (int i2 = 0; i2 < 4; ++i2)
      t[ty * 4 + i2][tx] = Wsrc[(size_t)(kb + ty * 4 + i2) * 512 + nb + tx];
    __syncthreads();
#pragma unroll
    for (int i2 = 0; i2 < 4; ++i2)
      dst[(size_t)(nb + ty * 4 + i2) * stride + colOff + kb + tx] = bf16one(t[tx][ty * 4 + i2]);
  }
}

// ---------------- degree / CSR ----------------
__global__ void k_accum(const int* col, const float* w, float* deg, int* cnt) {
  int e = blockIdx.x * 256 + threadIdx.x;
  if (e < NE) {
    int c = col[e];
    atomicAdd(&deg[c], w[e]);
    atomicAdd(&cnt[c], 1);
  }
}

__global__ void k_scan(const int* cnt, int* ptr, int* pos) {
  __shared__ int sdata[1024];
  const int ITEMS = (NN + 1023) / 1024;
  int tid = threadIdx.x;
  int base = tid * ITEMS;
  int s = 0;
  for (int j = 0; j < ITEMS; ++j) { int i = base + j; if (i < NN) s += cnt[i]; }
  sdata[tid] = s;
  __syncthreads();
  for (int off = 1; off < 1024; off <<= 1) {
    int v = 0;
    if (tid >= off) v = sdata[tid - off];
    __syncthreads();
    sdata[tid] += v;
    __syncthreads();
  }
  int run = (tid == 0) ? 0 : sdata[tid - 1];
  for (int j = 0; j < ITEMS; ++j) {
    int i = base + j;
    if (i < NN) { ptr[i] = run; pos[i] = run; run += cnt[i]; }
  }
  if (tid == 0) ptr[NN] = NE;
}

__global__ void k_scatter(const int* row, const int* col, const float* w, const float* deg,
                          int* pos, int* erow, float* enorm) {
  int e = blockIdx.x * 256 + threadIdx.x;
  if (e < NE) {
    int r = row[e], c = col[e];
    int slot = atomicAdd(&pos[c], 1);
    erow[slot] = r;
    enorm[slot] = rsqrtf(deg[r]) * w[e] * rsqrtf(deg[c]);
  }
}

// ---------------- XCD-sliced single-array aggregation, strided dest ----------------
// grid 2*AGG_B: blocks [0,AGG_B) aggregate SA->DA, [AGG_B,2*AGG_B) SB->DB
// (time-separated so each XCD's L2 holds ONE 2.56MB array slice).
// quarter (16 lanes) = one node; g0 = self + odd-offset edges, g1 = even. unroll-4.
// dest row stride dstride4 (uint4 units) supports interleaved AXH writes.
#define AGG_B 10000
__global__ __launch_bounds__(256) void k_agg_one(const u16* __restrict__ SA,
                                                 const u16* __restrict__ SB,
                                                 u16* __restrict__ DA,
                                                 u16* __restrict__ DB,
                                                 const int* __restrict__ ptr,
                                                 const int* __restrict__ erow,
                                                 const float* __restrict__ enorm,
                                                 const float* __restrict__ deg,
                                                 int dstride4) {
  int bid = blockIdx.x;
  bool second = bid >= AGG_B;
  const uint4* S4 = (const uint4*)(second ? SB : SA);
  uint4* D4 = (uint4*)(second ? DB : DA);
  int b = second ? bid - AGG_B : bid;
  int slice = b & 7, nb = b >> 3;
  int w = threadIdx.x >> 6, lane = threadIdx.x & 63;
  int node = nb * 16 + w * 4 + (lane >> 4);
  int q = lane & 15;
  int g = q >> 3, cl = q & 7;
  int soff = slice * 8 + cl;

  float s = rsqrtf(deg[node]), s2 = s * s;
  int pe = ptr[node], e1 = ptr[node + 1];

  f32x2 ax[4] = {};
  auto accum = [&](float nm, uint4 xv) {
    unsigned xw[4] = {xv.x, xv.y, xv.z, xv.w};
    f32x2 nm2 = {nm, nm};
#pragma unroll
    for (int j = 0; j < 4; ++j) {
      f32x2 xf = {bflo(xw[j]), bfhi(xw[j])};
      ax[j] += nm2 * xf;   // v_pk_fma_f32
    }
  };

  if (g == 0) accum(s2, S4[(size_t)node * 64 + soff]);   // self-loop
  int e = pe + 1 - g;                                    // g0: odd offsets, g1: even
  for (; e + 6 < e1; e += 8) {
    int r0 = erow[e];     float n0 = enorm[e];
    int r1 = erow[e + 2]; float n1 = enorm[e + 2];
    int r2 = erow[e + 4]; float n2 = enorm[e + 4];
    int r3 = erow[e + 6]; float n3 = enorm[e + 6];
    uint4 x0 = S4[(size_t)r0 * 64 + soff];
    uint4 x1 = S4[(size_t)r1 * 64 + soff];
    uint4 x2 = S4[(size_t)r2 * 64 + soff];
    uint4 x3 = S4[(size_t)r3 * 64 + soff];
    accum(n0, x0);
    accum(n1, x1);
    accum(n2, x2);
    accum(n3, x3);
  }
  for (; e < e1; e += 2) accum(enorm[e], S4[(size_t)erow[e] * 64 + soff]);

  // single butterfly stage: combine the quarter's two groups
#pragma unroll
  for (int j = 0; j < 4; ++j) {
    ax[j].x += __shfl_xor(ax[j].x, 8, 64);
    ax[j].y += __shfl_xor(ax[j].y, 8, 64);
  }

  if (g == 0) {
    uint4 ox = {bf16pair(ax[0].x, ax[0].y), bf16pair(ax[1].x, ax[1].y),
                bf16pair(ax[2].x, ax[2].y), bf16pair(ax[3].x, ax[3].y)};
    D4[(size_t)node * dstride4 + soff] = ox;
  }
}

// ---------------- z&r GEMM: single-pass K=1024 over interleaved A/Wcat ----------
// A = AXH [NP][1024] (cols 0-511 = AX, 512-1023 = AH), stride 2048B.
// seg 0 (c 0-3):  Zb  = bf16(sigmoid(AXH@Wcat_z + bxz+bhz))
// seg 1 (c 4-7):  HRb = bf16(Hb * sigmoid(AXH@Wcat_r + bxr+bhr))
__global__ __launch_bounds__(256) void k_gemm_big(
    const u16* __restrict__ AXH, const u16* __restrict__ WtAll,
    const float* __restrict__ bxz, const float* __restrict__ bhz,
    const float* __restrict__ bxr, const float* __restrict__ bhr,
    const u16* __restrict__ Hb,
    u16* __restrict__ Zb, u16* __restrict__ HRb) {
  __shared__ unsigned char smem[32768];
  const int tid = threadIdx.x;
  const int lane = tid & 63, w = tid >> 6;
  const int wr = w >> 1, wc = w & 1;

  // bijective XCD-chunked map over 1256 = 157 row-blocks x 8 col-blocks (1256 = 8*157)
  const int q = 157;
  const int xcd = blockIdx.x & 7, ii = blockIdx.x >> 3;
  const int wk = xcd * q + ii;
  const int rowBase = (wk >> 3) * 128;
  const int c = wk & 7;
  const int seg = c >> 2;
  const int colBase = (c & 3) * 128;

  const u16* Wt = WtAll + (seg ? OFF_WR : OFF_WZ);

  f32x4 acc[4][4] = {};

  const int lrow = lane & 15;
  const int lkb = (lane >> 4) << 4;
  const int swz = (lane & 7) << 4;
  const int srow = w * 32 + (lane >> 3);
  const int scol = (((lane & 7) ^ (lane >> 3)) << 4);

  const char* Abase = (const char*)AXH + (size_t)(rowBase + srow) * 2048 + scol;
  const char* Bbase = (const char*)Wt + (size_t)(colBase + srow) * 2048 + scol;

  for (int kt = 0; kt < 16; ++kt) {
    size_t ko = (size_t)kt << 7;   // kt*128 bytes = 64 bf16 cols
    __syncthreads();
#pragma unroll
    for (int t = 0; t < 4; ++t) {
      gload16(Abase + (size_t)t * 8 * 2048 + ko, &smem[w * 4096 + t * 1024]);
      gload16(Bbase + (size_t)t * 8 * 2048 + ko, &smem[16384 + w * 4096 + t * 1024]);
    }
    __syncthreads();
#pragma unroll
    for (int ks = 0; ks < 2; ++ks) {
      bf16x8 af[4], bfr[4];
#pragma unroll
      for (int fm = 0; fm < 4; ++fm) {
        int row = wr * 64 + fm * 16 + lrow;
        af[fm] = *(const bf16x8*)&smem[row * 128 + (((ks << 6) + lkb) ^ swz)];
      }
#pragma unroll
      for (int fn = 0; fn < 4; ++fn) {
        int row = wc * 64 + fn * 16 + lrow;
        bfr[fn] = *(const bf16x8*)&smem[16384 + row * 128 + (((ks << 6) + lkb) ^ swz)];
      }
#pragma unroll
      for (int fm = 0; fm < 4; ++fm)
#pragma unroll
        for (int fn = 0; fn < 4; ++fn)
          acc[fm][fn] = __builtin_amdgcn_mfma_f32_16x16x32_bf16(af[fm], bfr[fn], acc[fm][fn], 0, 0, 0);
    }
  }
  // epilogue: col=lane&15, row=(lane>>4)*4+reg
#pragma unroll
  for (int fm = 0; fm < 4; ++fm) {
    int rbase = rowBase + wr * 64 + fm * 16 + ((lane >> 4) << 2);
#pragma unroll
    for (int fn = 0; fn < 4; ++fn) {
      int col = colBase + wc * 64 + fn * 16 + lrow;
      float bb = seg ? (bxr[col] + bhr[col]) : (bxz[col] + bhz[col]);
#pragma unroll
      for (int r = 0; r < 4; ++r) {
        int row = rbase + r;
        if (row >= NN) continue;
        size_t idx = (size_t)row * 512 + col;
        float a = acc[fm][fn][r] + bb;
        if (seg == 0) {
          Zb[idx] = bf16one(sigmoidf_(a));
        } else {
          HRb[idx] = bf16one(bf2f(Hb[idx]) * sigmoidf_(a));
        }
      }
    }
  }
}

// ---------------- final GEMM: 2-pass K (A strides differ), fused gate epilogue ----
// pass 0: AHRb [NP][512] @ Whh_t; pass 1: AX (= AXH cols 0-511, stride 2048B) @ Wxh_t.
__global__ __launch_bounds__(256) void k_gemm_fin(
    const u16* __restrict__ AHRb, const u16* __restrict__ AXH,
    const u16* __restrict__ WtAll,
    const float* __restrict__ bxh, const float* __restrict__ bhh,
    const u16* __restrict__ Hb, const u16* __restrict__ Zb,
    float* __restrict__ out) {
  __shared__ unsigned char smem[32768];
  const int tid = threadIdx.x;
  const int lane = tid & 63, w = tid >> 6;
  const int wr = w >> 1, wc = w & 1;

  const int q = 78, r8 = 4;  // 628 = 8*78+4
  const int xcd = blockIdx.x & 7, ii = blockIdx.x >> 3;
  const int start = (xcd < r8) ? xcd * (q + 1) : r8 * (q + 1) + (xcd - r8) * q;
  const int wk = start + ii;
  const int rowBase = (wk >> 2) * 128;
  const int colBase = (wk & 3) * 128;

  f32x4 acc[4][4] = {};

  const int lrow = lane & 15;
  const int lkb = (lane >> 4) << 4;
  const int swz = (lane & 7) << 4;
  const int srow = w * 32 + (lane >> 3);
  const int scol = (((lane & 7) ^ (lane >> 3)) << 4);

  for (int pass = 0; pass < 2; ++pass) {
    const char* Abase;
    size_t strideA;
    if (pass == 0) {
      Abase = (const char*)AHRb + (size_t)(rowBase + srow) * 1024 + scol;
      strideA = 1024;
    } else {
      Abase = (const char*)AXH + (size_t)(rowBase + srow) * 2048 + scol;
      strideA = 2048;
    }
    const u16* Wt = WtAll + (pass ? OFF_WXH : OFF_WHH);
    const char* Bbase = (const char*)Wt + (size_t)(colBase + srow) * 1024 + scol;
    for (int kt = 0; kt < 8; ++kt) {
      size_t ko = (size_t)kt << 7;
      __syncthreads();
#pragma unroll
      for (int t = 0; t < 4; ++t) {
        gload16(Abase + (size_t)t * 8 * strideA + ko, &smem[w * 4096 + t * 1024]);
        gload16(Bbase + (size_t)t * 8 * 1024 + ko, &smem[16384 + w * 4096 + t * 1024]);
      }
      __syncthreads();
#pragma unroll
      for (int ks = 0; ks < 2; ++ks) {
        bf16x8 af[4], bfr[4];
#pragma unroll
        for (int fm = 0; fm < 4; ++fm) {
          int row = wr * 64 + fm * 16 + lrow;
          af[fm] = *(const bf16x8*)&smem[row * 128 + (((ks << 6) + lkb) ^ swz)];
        }
#pragma unroll
        for (int fn = 0; fn < 4; ++fn) {
          int row = wc * 64 + fn * 16 + lrow;
          bfr[fn] = *(const bf16x8*)&smem[16384 + row * 128 + (((ks << 6) + lkb) ^ swz)];
        }
#pragma unroll
        for (int fm = 0; fm < 4; ++fm)
#pragma unroll
          for (int fn = 0; fn < 4; ++fn)
            acc[fm][fn] = __builtin_amdgcn_mfma_f32_16x16x32_bf16(af[fm], bfr[fn], acc[fm][fn], 0, 0, 0);
      }
    }
  }
#pragma unroll
  for (int fm = 0; fm < 4; ++fm) {
    int rbase = rowBase + wr * 64 + fm * 16 + ((lane >> 4) << 2);
#pragma unroll
    for (int fn = 0; fn < 4; ++fn) {
      int col = colBase + wc * 64 + fn * 16 + lrow;
      float bb = bxh[col] + bhh[col];
#pragma unroll
      for (int r = 0; r < 4; ++r) {
        int row = rbase + r;
        if (row >= NN) continue;
        size_t idx = (size_t)row * 512 + col;
        float t = tanhf_(acc[fm][fn][r] + bb);
        float z = bf2f(Zb[idx]);
        float h = bf2f(Hb[idx]);
        out[idx] = z * h + (1.f - z) * t;
      }
    }
  }
}

extern "C" void kernel_launch(void* const* d_in, const int* in_sizes, int n_in,
                              void* d_out, int out_size, void* d_ws, size_t ws_size,
                              hipStream_t stream) {
  const float* X   = (const float*)d_in[0];
  const int*   ei  = (const int*)d_in[1];
  const float* ew  = (const float*)d_in[2];
  const float* H   = (const float*)d_in[3];
  const float* Wxz = (const float*)d_in[4];  const float* bxz = (const float*)d_in[5];
  const float* Whz = (const float*)d_in[6];  const float* bhz = (const float*)d_in[7];
  const float* Wxr = (const float*)d_in[8];  const float* bxr = (const float*)d_in[9];
  const float* Whr = (const float*)d_in[10]; const float* bhr = (const float*)d_in[11];
  const float* Wxh = (const float*)d_in[12]; const float* bxh = (const float*)d_in[13];
  const float* Whh = (const float*)d_in[14]; const float* bhh = (const float*)d_in[15];
  const int* row = ei;
  const int* col = ei + NE;
  float* out = (float*)d_out;

  char* base = (char*)d_ws;
  size_t o = 0;
  auto alloc = [&](size_t b) { char* p = base + o; o += (b + 255) & ~(size_t)255; return p; };
  u16* Xb   = (u16*)alloc((size_t)NP * DD * 2);   // aliases AHRb (Xb dead after agg X/H)
  u16* Hb   = (u16*)alloc((size_t)NP * DD * 2);   // live through gemm_fin epilogue
  u16* AXH  = (u16*)alloc((size_t)NP * 1024 * 2); // interleaved AX|AH, live through fin
  u16* HRb  = (u16*)alloc((size_t)NP * DD * 2);
  u16* Zb   = (u16*)alloc((size_t)NP * DD * 2);
  u16* WtAll= (u16*)alloc((size_t)6 * 512 * 512 * 2);
  float* deg  = (float*)alloc(NN * 4);
  int*   cnt  = (int*)alloc(NN * 4);
  int*   ptr  = (int*)alloc((NN + 1) * 4);
  int*   pos  = (int*)alloc(NN * 4);
  int*   erow = (int*)alloc(NE * 4);
  float* enorm= (float*)alloc(NE * 4);
  u16* AHRb = Xb;   // Xb dead after the X/H aggregation

  dim3 b256(256);
  int gE = (NE + 255) / 256;

  // fused setup: cvt X/H -> bf16 | init deg/cnt | weight transposes (K-cat packed)
  k_setup<<<CVT_B + INIT_B + WT_B, b256, 0, stream>>>(
      X, H, Xb, Hb, Wxz, Whz, Wxr, Whr, Wxh, Whh, WtAll, deg, cnt);

  // CSR build
  k_accum<<<gE, b256, 0, stream>>>(col, ew, deg, cnt);
  k_scan<<<1, 1024, 0, stream>>>(cnt, ptr, pos);
  k_scatter<<<gE, b256, 0, stream>>>(row, col, ew, deg, pos, erow, enorm);

  // AX -> AXH[:,0:512], AH -> AXH[:,512:1024]; time-separated (L2-slice-fit)
  k_agg_one<<<2 * AGG_B, b256, 0, stream>>>(Xb, Hb, AXH, AXH + 512,
                                            ptr, erow, enorm, deg, 128);

  // z & r GEMM (single-pass K=1024) -> Zb, HRb
  k_gemm_big<<<1256, b256, 0, stream>>>(AXH, WtAll, bxz, bhz, bxr, bhr,
                                        Hb, Zb, HRb);

  // AHR = Agg(HR)
  k_agg_one<<<AGG_B, b256, 0, stream>>>(HRb, HRb, AHRb, AHRb,
                                        ptr, erow, enorm, deg, 64);

  // out = z*h + (1-z)*tanh(AHR@Whh + AX@Wxh + bxh + bhh)
  k_gemm_fin<<<628, b256, 0, stream>>>(AHRb, AXH, WtAll, bxh, bhh,
                                       Hb, Zb, out);
}

// Round 17
// 320.061 us; speedup vs baseline: 1.0096x; 1.0096x over previous
//
#include <hip/hip_runtime.h>

#define NN 20000
#define NP 20096   // padded rows (multiple of 128)
#define NE 320000
#define DD 512

typedef __bf16 bf16x8 __attribute__((ext_vector_type(8)));
typedef float f32x4 __attribute__((ext_vector_type(4)));
typedef float f32x2 __attribute__((ext_vector_type(2)));
typedef unsigned short u16;

// fast transcendentals: v_exp_f32 + v_rcp_f32, branchless
__device__ __forceinline__ float sigmoidf_(float x) {
  return __builtin_amdgcn_rcpf(1.f + __expf(-x));
}
__device__ __forceinline__ float tanhf_(float x) {
  float xc = fminf(fmaxf(x, -15.f), 15.f);
  float u = __expf(2.f * xc);
  return (u - 1.f) * __builtin_amdgcn_rcpf(u + 1.f);
}

__device__ __forceinline__ unsigned bf16pair(float a, float b) {
  unsigned ua = __builtin_bit_cast(unsigned, a);
  unsigned ub = __builtin_bit_cast(unsigned, b);
  ua = (ua + 0x7FFFu + ((ua >> 16) & 1u)) >> 16;
  ub = (ub + 0x7FFFu + ((ub >> 16) & 1u)) >> 16;
  return ua | (ub << 16);
}
__device__ __forceinline__ u16 bf16one(float a) {
  unsigned ua = __builtin_bit_cast(unsigned, a);
  return (u16)((ua + 0x7FFFu + ((ua >> 16) & 1u)) >> 16);
}
__device__ __forceinline__ float bflo(unsigned w) { return __builtin_bit_cast(float, w << 16); }
__device__ __forceinline__ float bfhi(unsigned w) { return __builtin_bit_cast(float, w & 0xFFFF0000u); }
__device__ __forceinline__ float bf2f(u16 v) { return __builtin_bit_cast(float, (unsigned)v << 16); }

__device__ __forceinline__ void gload16(const void* g, void* l) {
  __builtin_amdgcn_global_load_lds(
      (const __attribute__((address_space(1))) unsigned int*)g,
      (__attribute__((address_space(3))) unsigned int*)l, 16, 0, 0);
}

// ---------------- fused setup: cvt(X,H)->bf16 | init deg/cnt | 6 weight transposes ----
#define CVT_B 10000   // 2*NN*DD/8/256
#define INIT_B 79     // ceil(NN/256)
#define WT_B 1536     // 6 * 16 * 16
__global__ __launch_bounds__(256) void k_setup(
    const float* __restrict__ X, const float* __restrict__ H,
    u16* __restrict__ Xb, u16* __restrict__ Hb,
    const float* __restrict__ W0, const float* __restrict__ W1,
    const float* __restrict__ W2, const float* __restrict__ W3,
    const float* __restrict__ W4, const float* __restrict__ W5,
    u16* __restrict__ T, float* __restrict__ deg, int* __restrict__ cnt) {
  __shared__ float t[32][33];
  int b = blockIdx.x;
  if (b < CVT_B) {
    const int n8 = NN * DD / 8;
    int i = b * 256 + threadIdx.x;
    const float* src = (i < n8) ? X : H;
    u16* dst = (i < n8) ? Xb : Hb;
    int k = (i < n8) ? i : i - n8;
    const float4* s = (const float4*)src;
    float4 v0 = s[k * 2], v1 = s[k * 2 + 1];
    uint4 o = {bf16pair(v0.x, v0.y), bf16pair(v0.z, v0.w),
               bf16pair(v1.x, v1.y), bf16pair(v1.z, v1.w)};
    ((uint4*)dst)[k] = o;
  } else if (b < CVT_B + INIT_B) {
    int i = (b - CVT_B) * 256 + threadIdx.x;
    if (i < NN) { deg[i] = 1.0f; cnt[i] = 0; }
  } else {
    int wb = b - CVT_B - INIT_B;          // [0, 1536)
    const float* Wsrc;
    switch (wb >> 8) {
      case 0: Wsrc = W0; break; case 1: Wsrc = W1; break; case 2: Wsrc = W2; break;
      case 3: Wsrc = W3; break; case 4: Wsrc = W4; break; default: Wsrc = W5; break;
    }
    u16* Wt = T + (size_t)(wb >> 8) * 262144;
    int rb = wb & 255;
    int kb = (rb & 15) * 32, nb = (rb >> 4) * 32;
    int tx = threadIdx.x & 31, ty = threadIdx.x >> 5;
#pragma unroll
    for (int i2 = 0; i2 < 4; ++i2)
      t[ty * 4 + i2][tx] = Wsrc[(size_t)(kb + ty * 4 + i2) * 512 + nb + tx];
    __syncthreads();
#pragma unroll
    for (int i2 = 0; i2 < 4; ++i2)
      Wt[(size_t)(nb + ty * 4 + i2) * 512 + kb + tx] = bf16one(t[tx][ty * 4 + i2]);
  }
}

// ---------------- degree / CSR ----------------
__global__ void k_accum(const int* col, const float* w, float* deg, int* cnt) {
  int e = blockIdx.x * 256 + threadIdx.x;
  if (e < NE) {
    int c = col[e];
    atomicAdd(&deg[c], w[e]);
    atomicAdd(&cnt[c], 1);
  }
}

__global__ void k_scan(const int* cnt, int* ptr, int* pos) {
  __shared__ int sdata[1024];
  const int ITEMS = (NN + 1023) / 1024;
  int tid = threadIdx.x;
  int base = tid * ITEMS;
  int s = 0;
  for (int j = 0; j < ITEMS; ++j) { int i = base + j; if (i < NN) s += cnt[i]; }
  sdata[tid] = s;
  __syncthreads();
  for (int off = 1; off < 1024; off <<= 1) {
    int v = 0;
    if (tid >= off) v = sdata[tid - off];
    __syncthreads();
    sdata[tid] += v;
    __syncthreads();
  }
  int run = (tid == 0) ? 0 : sdata[tid - 1];
  for (int j = 0; j < ITEMS; ++j) {
    int i = base + j;
    if (i < NN) { ptr[i] = run; pos[i] = run; run += cnt[i]; }
  }
  if (tid == 0) ptr[NN] = NE;
}

__global__ void k_scatter(const int* row, const int* col, const float* w, const float* deg,
                          int* pos, int* erow, float* enorm) {
  int e = blockIdx.x * 256 + threadIdx.x;
  if (e < NE) {
    int r = row[e], c = col[e];
    int slot = atomicAdd(&pos[c], 1);
    erow[slot] = r;
    enorm[slot] = rsqrtf(deg[r]) * w[e] * rsqrtf(deg[c]);
  }
}

// ---------------- XCD-sliced single-array aggregation ----------------
// grid 2*AGG_B: blocks [0,AGG_B) aggregate SA->DA, [AGG_B,2*AGG_B) SB->DB
// (time-separated so each XCD's L2 holds ONE 2.56MB array slice).
// quarter (16 lanes) = one node; group g in {0,1}: g0 = self + odd-offset edges,
// g1 = even-offset edges. unroll-4. Tail: ONE shfl_xor stage (stride 8).
#define AGG_B 10000
__global__ __launch_bounds__(256) void k_agg_one(const u16* __restrict__ SA,
                                                 const u16* __restrict__ SB,
                                                 u16* __restrict__ DA,
                                                 u16* __restrict__ DB,
                                                 const int* __restrict__ ptr,
                                                 const int* __restrict__ erow,
                                                 const float* __restrict__ enorm,
                                                 const float* __restrict__ deg) {
  int bid = blockIdx.x;
  bool second = bid >= AGG_B;
  const uint4* S4 = (const uint4*)(second ? SB : SA);
  uint4* D4 = (uint4*)(second ? DB : DA);
  int b = second ? bid - AGG_B : bid;
  int slice = b & 7, nb = b >> 3;
  int w = threadIdx.x >> 6, lane = threadIdx.x & 63;
  int node = nb * 16 + w * 4 + (lane >> 4);
  int q = lane & 15;
  int g = q >> 3, cl = q & 7;
  int soff = slice * 8 + cl;

  float s = rsqrtf(deg[node]), s2 = s * s;
  int pe = ptr[node], e1 = ptr[node + 1];

  f32x2 ax[4] = {};
  auto accum = [&](float nm, uint4 xv) {
    unsigned xw[4] = {xv.x, xv.y, xv.z, xv.w};
    f32x2 nm2 = {nm, nm};
#pragma unroll
    for (int j = 0; j < 4; ++j) {
      f32x2 xf = {bflo(xw[j]), bfhi(xw[j])};
      ax[j] += nm2 * xf;   // v_pk_fma_f32
    }
  };

  if (g == 0) accum(s2, S4[(size_t)node * 64 + soff]);   // self-loop
  int e = pe + 1 - g;                                    // g0: odd offsets, g1: even
  for (; e + 6 < e1; e += 8) {
    int r0 = erow[e];     float n0 = enorm[e];
    int r1 = erow[e + 2]; float n1 = enorm[e + 2];
    int r2 = erow[e + 4]; float n2 = enorm[e + 4];
    int r3 = erow[e + 6]; float n3 = enorm[e + 6];
    uint4 x0 = S4[(size_t)r0 * 64 + soff];
    uint4 x1 = S4[(size_t)r1 * 64 + soff];
    uint4 x2 = S4[(size_t)r2 * 64 + soff];
    uint4 x3 = S4[(size_t)r3 * 64 + soff];
    accum(n0, x0);
    accum(n1, x1);
    accum(n2, x2);
    accum(n3, x3);
  }
  for (; e < e1; e += 2) accum(enorm[e], S4[(size_t)erow[e] * 64 + soff]);

  // single butterfly stage: combine the quarter's two groups
#pragma unroll
  for (int j = 0; j < 4; ++j) {
    ax[j].x += __shfl_xor(ax[j].x, 8, 64);
    ax[j].y += __shfl_xor(ax[j].y, 8, 64);
  }

  if (g == 0) {
    uint4 ox = {bf16pair(ax[0].x, ax[0].y), bf16pair(ax[1].x, ax[1].y),
                bf16pair(ax[2].x, ax[2].y), bf16pair(ax[3].x, ax[3].y)};
    D4[(size_t)node * 64 + soff] = ox;
  }
}

// ---------------- z&r GEMM: 8 col-blocks (z | r), round-9 proven structure ----------
// seg 0 (c 0-3):  Zb  = bf16(sigmoid(AX@Wxz + AH@Whz + bxz+bhz))
// seg 1 (c 4-7):  HRb = bf16(Hb * sigmoid(AX@Wxr + AH@Whr + bxr+bhr))
__global__ __launch_bounds__(256) void k_gemm_big(
    const u16* __restrict__ AXb, const u16* __restrict__ AHb,
    const u16* __restrict__ WtAll,
    const float* __restrict__ bxz, const float* __restrict__ bhz,
    const float* __restrict__ bxr, const float* __restrict__ bhr,
    const u16* __restrict__ Hb,
    u16* __restrict__ Zb, u16* __restrict__ HRb) {
  __shared__ unsigned char smem[32768];
  const int tid = threadIdx.x;
  const int lane = tid & 63, w = tid >> 6;
  const int wr = w >> 1, wc = w & 1;

  // bijective XCD-chunked map over 1256 = 157 row-blocks x 8 col-blocks (1256 = 8*157)
  const int q = 157;
  const int xcd = blockIdx.x & 7, ii = blockIdx.x >> 3;
  const int wk = xcd * q + ii;
  const int rowBase = (wk >> 3) * 128;
  const int c = wk & 7;
  const int seg = c >> 2;
  const int colBase = (c & 3) * 128;

  const u16* W1 = WtAll + (size_t)(seg ? 2 : 0) * 262144;
  const u16* W2 = WtAll + (size_t)(seg ? 3 : 1) * 262144;

  f32x4 acc[4][4] = {};

  const int lrow = lane & 15;
  const int lkb = (lane >> 4) << 4;
  const int swz = (lane & 7) << 4;
  const int srow = w * 32 + (lane >> 3);
  const int scol = (((lane & 7) ^ (lane >> 3)) << 4);

  for (int pass = 0; pass < 2; ++pass) {
    const u16* A = pass ? AHb : AXb;
    const u16* Wt = pass ? W2 : W1;
    const char* Abase = (const char*)A + (size_t)(rowBase + srow) * 1024 + scol;
    const char* Bbase = (const char*)Wt + (size_t)(colBase + srow) * 1024 + scol;
    for (int k0 = 0; k0 < 512; k0 += 64) {
      __syncthreads();
#pragma unroll
      for (int t = 0; t < 4; ++t) {
        gload16(Abase + (size_t)t * 8192 + k0 * 2, &smem[w * 4096 + t * 1024]);
        gload16(Bbase + (size_t)t * 8192 + k0 * 2, &smem[16384 + w * 4096 + t * 1024]);
      }
      __syncthreads();
#pragma unroll
      for (int ks = 0; ks < 2; ++ks) {
        bf16x8 af[4], bfr[4];
#pragma unroll
        for (int fm = 0; fm < 4; ++fm) {
          int row = wr * 64 + fm * 16 + lrow;
          af[fm] = *(const bf16x8*)&smem[row * 128 + (((ks << 6) + lkb) ^ swz)];
        }
#pragma unroll
        for (int fn = 0; fn < 4; ++fn) {
          int row = wc * 64 + fn * 16 + lrow;
          bfr[fn] = *(const bf16x8*)&smem[16384 + row * 128 + (((ks << 6) + lkb) ^ swz)];
        }
#pragma unroll
        for (int fm = 0; fm < 4; ++fm)
#pragma unroll
          for (int fn = 0; fn < 4; ++fn)
            acc[fm][fn] = __builtin_amdgcn_mfma_f32_16x16x32_bf16(af[fm], bfr[fn], acc[fm][fn], 0, 0, 0);
      }
    }
  }
  // epilogue: col=lane&15, row=(lane>>4)*4+reg
#pragma unroll
  for (int fm = 0; fm < 4; ++fm) {
    int rbase = rowBase + wr * 64 + fm * 16 + ((lane >> 4) << 2);
#pragma unroll
    for (int fn = 0; fn < 4; ++fn) {
      int col = colBase + wc * 64 + fn * 16 + lrow;
      float bb = seg ? (bxr[col] + bhr[col]) : (bxz[col] + bhz[col]);
#pragma unroll
      for (int r = 0; r < 4; ++r) {
        int row = rbase + r;
        if (row >= NN) continue;
        size_t idx = (size_t)row * 512 + col;
        float a = acc[fm][fn][r] + bb;
        if (seg == 0) {
          Zb[idx] = bf16one(sigmoidf_(a));
        } else {
          HRb[idx] = bf16one(bf2f(Hb[idx]) * sigmoidf_(a));
        }
      }
    }
  }
}

// ---------------- final GEMM: 2-pass K, out = z*h + (1-z)*tanh(AHR@Whh + AX@Wxh + b) --
__global__ __launch_bounds__(256) void k_gemm_fin(
    const u16* __restrict__ AHRb, const u16* __restrict__ AXb,
    const u16* __restrict__ WtAll,
    const float* __restrict__ bxh, const float* __restrict__ bhh,
    const u16* __restrict__ Hb, const u16* __restrict__ Zb,
    float* __restrict__ out) {
  __shared__ unsigned char smem[32768];
  const int tid = threadIdx.x;
  const int lane = tid & 63, w = tid >> 6;
  const int wr = w >> 1, wc = w & 1;

  const int q = 78, r8 = 4;  // 628 = 8*78+4
  const int xcd = blockIdx.x & 7, ii = blockIdx.x >> 3;
  const int start = (xcd < r8) ? xcd * (q + 1) : r8 * (q + 1) + (xcd - r8) * q;
  const int wk = start + ii;
  const int rowBase = (wk >> 2) * 128;
  const int colBase = (wk & 3) * 128;

  f32x4 acc[4][4] = {};

  const int lrow = lane & 15;
  const int lkb = (lane >> 4) << 4;
  const int swz = (lane & 7) << 4;
  const int srow = w * 32 + (lane >> 3);
  const int scol = (((lane & 7) ^ (lane >> 3)) << 4);

  for (int pass = 0; pass < 2; ++pass) {
    const u16* A  = pass ? AXb : AHRb;
    const u16* Wt = WtAll + (size_t)(pass ? 4 : 5) * 262144;  // Whh then Wxh
    const char* Abase = (const char*)A + (size_t)(rowBase + srow) * 1024 + scol;
    const char* Bbase = (const char*)Wt + (size_t)(colBase + srow) * 1024 + scol;
    for (int k0 = 0; k0 < 512; k0 += 64) {
      __syncthreads();
#pragma unroll
      for (int t = 0; t < 4; ++t) {
        gload16(Abase + (size_t)t * 8192 + k0 * 2, &smem[w * 4096 + t * 1024]);
        gload16(Bbase + (size_t)t * 8192 + k0 * 2, &smem[16384 + w * 4096 + t * 1024]);
      }
      __syncthreads();
#pragma unroll
      for (int ks = 0; ks < 2; ++ks) {
        bf16x8 af[4], bfr[4];
#pragma unroll
        for (int fm = 0; fm < 4; ++fm) {
          int row = wr * 64 + fm * 16 + lrow;
          af[fm] = *(const bf16x8*)&smem[row * 128 + (((ks << 6) + lkb) ^ swz)];
        }
#pragma unroll
        for (int fn = 0; fn < 4; ++fn) {
          int row = wc * 64 + fn * 16 + lrow;
          bfr[fn] = *(const bf16x8*)&smem[16384 + row * 128 + (((ks << 6) + lkb) ^ swz)];
        }
#pragma unroll
        for (int fm = 0; fm < 4; ++fm)
#pragma unroll
          for (int fn = 0; fn < 4; ++fn)
            acc[fm][fn] = __builtin_amdgcn_mfma_f32_16x16x32_bf16(af[fm], bfr[fn], acc[fm][fn], 0, 0, 0);
      }
    }
  }
#pragma unroll
  for (int fm = 0; fm < 4; ++fm) {
    int rbase = rowBase + wr * 64 + fm * 16 + ((lane >> 4) << 2);
#pragma unroll
    for (int fn = 0; fn < 4; ++fn) {
      int col = colBase + wc * 64 + fn * 16 + lrow;
      float bb = bxh[col] + bhh[col];
#pragma unroll
      for (int r = 0; r < 4; ++r) {
        int row = rbase + r;
        if (row >= NN) continue;
        size_t idx = (size_t)row * 512 + col;
        float t = tanhf_(acc[fm][fn][r] + bb);
        float z = bf2f(Zb[idx]);
        float h = bf2f(Hb[idx]);
        out[idx] = z * h + (1.f - z) * t;
      }
    }
  }
}

extern "C" void kernel_launch(void* const* d_in, const int* in_sizes, int n_in,
                              void* d_out, int out_size, void* d_ws, size_t ws_size,
                              hipStream_t stream) {
  const float* X   = (const float*)d_in[0];
  const int*   ei  = (const int*)d_in[1];
  const float* ew  = (const float*)d_in[2];
  const float* H   = (const float*)d_in[3];
  const float* Wxz = (const float*)d_in[4];  const float* bxz = (const float*)d_in[5];
  const float* Whz = (const float*)d_in[6];  const float* bhz = (const float*)d_in[7];
  const float* Wxr = (const float*)d_in[8];  const float* bxr = (const float*)d_in[9];
  const float* Whr = (const float*)d_in[10]; const float* bhr = (const float*)d_in[11];
  const float* Wxh = (const float*)d_in[12]; const float* bxh = (const float*)d_in[13];
  const float* Whh = (const float*)d_in[14]; const float* bhh = (const float*)d_in[15];
  const int* row = ei;
  const int* col = ei + NE;
  float* out = (float*)d_out;

  char* base = (char*)d_ws;
  size_t o = 0;
  auto alloc = [&](size_t b) { char* p = base + o; o += (b + 255) & ~(size_t)255; return p; };
  u16* Xb   = (u16*)alloc((size_t)NP * DD * 2);  // aliases AHRb (Xb dead after agg X/H)
  u16* Hb   = (u16*)alloc((size_t)NP * DD * 2);  // live through gemm_fin epilogue
  u16* AXb  = (u16*)alloc((size_t)NP * DD * 2);  // live through gemm_fin pass 2
  u16* AHb  = (u16*)alloc((size_t)NP * DD * 2);
  u16* HRb  = (u16*)alloc((size_t)NP * DD * 2);
  u16* Zb   = (u16*)alloc((size_t)NP * DD * 2);
  u16* WtAll= (u16*)alloc((size_t)6 * 512 * 512 * 2);
  float* deg  = (float*)alloc(NN * 4);
  int*   cnt  = (int*)alloc(NN * 4);
  int*   ptr  = (int*)alloc((NN + 1) * 4);
  int*   pos  = (int*)alloc(NN * 4);
  int*   erow = (int*)alloc(NE * 4);
  float* enorm= (float*)alloc(NE * 4);
  u16* AHRb = Xb;   // Xb dead after the X/H aggregation

  dim3 b256(256);
  int gE = (NE + 255) / 256;

  // fused setup: cvt X/H -> bf16 | init deg/cnt | 6 weight transposes
  k_setup<<<CVT_B + INIT_B + WT_B, b256, 0, stream>>>(
      X, H, Xb, Hb, Wxz, Whz, Wxr, Whr, Wxh, Whh, WtAll, deg, cnt);

  // CSR build
  k_accum<<<gE, b256, 0, stream>>>(col, ew, deg, cnt);
  k_scan<<<1, 1024, 0, stream>>>(cnt, ptr, pos);
  k_scatter<<<gE, b256, 0, stream>>>(row, col, ew, deg, pos, erow, enorm);

  // AX = Agg(X) then AH = Agg(H), time-separated in one launch (L2-slice-fit)
  k_agg_one<<<2 * AGG_B, b256, 0, stream>>>(Xb, Hb, AXb, AHb, ptr, erow, enorm, deg);

  // z & r GEMM -> Zb, HRb
  k_gemm_big<<<1256, b256, 0, stream>>>(AXb, AHb, WtAll, bxz, bhz, bxr, bhr,
                                        Hb, Zb, HRb);

  // AHR = Agg(HR)
  k_agg_one<<<AGG_B, b256, 0, stream>>>(HRb, HRb, AHRb, AHRb, ptr, erow, enorm, deg);

  // out = z*h + (1-z)*tanh(AHR@Whh + AX@Wxh + bxh + bhh)
  k_gemm_fin<<<628, b256, 0, stream>>>(AHRb, AXb, WtAll, bxh, bhh,
                                       Hb, Zb, out);
}